// Round 7
// baseline (1116.512 us; speedup 1.0000x reference)
//
#include <hip/hip_runtime.h>
#include <math.h>

// LDCA forward — bf16 MFMA GEMMs on channel-contiguous activations.
// B=4 C=256 H=W=96 HID=64 G=2 GC=32 KS=3 NK=9 MLP=1024

#define HH 96
#define WWD 96
#define HWP 9216
#define EPSV 1e-5f
#define RFV 9.0f

typedef unsigned short ushort;
typedef unsigned int uint;
typedef __attribute__((ext_vector_type(8))) short short8v;
typedef __attribute__((ext_vector_type(8))) ushort ushort8v;
typedef __attribute__((ext_vector_type(4))) float f32x4;

__device__ inline ushort f2bf(float f) {
  union { float f; unsigned u; } v; v.f = f;
  unsigned r = v.u + 0x7FFFu + ((v.u >> 16) & 1u);
  return (ushort)(r >> 16);
}
__device__ inline float bf2f(ushort h) {
  union { unsigned u; float f; } v; v.u = ((unsigned)h) << 16;
  return v.f;
}

__device__ inline void stf(float* p, float v) { *p = v; }
__device__ inline void stf(ushort* p, float v) { *p = f2bf(v); }

// stage 16 elements (f32->bf16 convert, or bf16 copy) into LDS
__device__ inline void stage16(const float* __restrict__ s, ushort* d) {
  const float4* s4 = (const float4*)s;
  float4 v0 = s4[0], v1 = s4[1], v2 = s4[2], v3 = s4[3];
  ushort8v r0, r1;
  r0[0] = f2bf(v0.x); r0[1] = f2bf(v0.y); r0[2] = f2bf(v0.z); r0[3] = f2bf(v0.w);
  r0[4] = f2bf(v1.x); r0[5] = f2bf(v1.y); r0[6] = f2bf(v1.z); r0[7] = f2bf(v1.w);
  r1[0] = f2bf(v2.x); r1[1] = f2bf(v2.y); r1[2] = f2bf(v2.z); r1[3] = f2bf(v2.w);
  r1[4] = f2bf(v3.x); r1[5] = f2bf(v3.y); r1[6] = f2bf(v3.z); r1[7] = f2bf(v3.w);
  ((ushort8v*)d)[0] = r0; ((ushort8v*)d)[1] = r1;
}
__device__ inline void stage16(const ushort* __restrict__ s, ushort* d) {
  ((ushort8v*)d)[0] = ((const ushort8v*)s)[0];
  ((ushort8v*)d)[1] = ((const ushort8v*)s)[1];
}

// ---------------- LN stats over Cn planar channels (per pixel) ----------------
__global__ __launch_bounds__(256) void k_ln_stats(const float* __restrict__ in,
                                                  float* __restrict__ mout,
                                                  float* __restrict__ rout, int Cn) {
  int idx = blockIdx.x * 256 + threadIdx.x;
  int b = idx / HWP, p = idx % HWP;
  const float* base = in + (size_t)b * Cn * HWP + p;
  float s = 0.f, ss = 0.f;
  for (int c = 0; c < Cn; ++c) { float v = base[(size_t)c * HWP]; s += v; ss += v * v; }
  float m = s / (float)Cn;
  float var = ss / (float)Cn - m * m;
  mout[idx] = m;
  rout[idx] = rsqrtf(var + EPSV);
}

// ---------------- LN stats, channel-contiguous input (256 ch) ----------------
__global__ __launch_bounds__(256) void k_ln_stats_cc(const float* __restrict__ in,
                                                     float* __restrict__ mout,
                                                     float* __restrict__ rout) {
  int px = blockIdx.x * 4 + (threadIdx.x >> 6);
  int lane = threadIdx.x & 63;
  float4 v = *(const float4*)(in + (size_t)px * 256 + lane * 4);
  float s = v.x + v.y + v.z + v.w;
  float ss = v.x * v.x + v.y * v.y + v.z * v.z + v.w * v.w;
#pragma unroll
  for (int d = 1; d < 64; d <<= 1) { s += __shfl_xor(s, d); ss += __shfl_xor(ss, d); }
  if (lane == 0) {
    float m = s / 256.f;
    mout[px] = m;
    rout[px] = rsqrtf(ss / 256.f - m * m + EPSV);
  }
}

// ---------------- prep: bf16 weights + LN-fold vectors (1 wave / row) ----------------
__global__ __launch_bounds__(256) void k_prepbf(const float* __restrict__ w,
                                                const float* __restrict__ g,
                                                const float* __restrict__ beta,
                                                ushort* __restrict__ wbf,
                                                float* __restrict__ sg, float* __restrict__ wb,
                                                int O, int K, int scaleRows) {
  int o = blockIdx.x * 4 + (threadIdx.x >> 6);
  int lane = threadIdx.x & 63;
  if (o >= O) return;
  float sc = (o < scaleRows) ? 0.125f : 1.f;
  float sgv = 0.f, wbv = 0.f;
  for (int c = lane; c < K; c += 64) {
    float wv = w[(size_t)o * K + c];
    float t = wv * (g ? g[c] : 1.f) * sc;
    ushort u = f2bf(t);
    wbf[(size_t)o * K + c] = u;
    sgv += bf2f(u);
    wbv += wv * (beta ? beta[c] : 0.f);
  }
#pragma unroll
  for (int d = 1; d < 64; d <<= 1) { sgv += __shfl_xor(sgv, d); wbv += __shfl_xor(wbv, d); }
  if (lane == 0) {
    if (sg) sg[o] = sgv;
    if (wb) wb[o] = wbv * sc;
  }
}

// ---------------- planar f32 -> channel-contiguous bf16 ----------------
__global__ __launch_bounds__(256) void k_tocc(const float* __restrict__ src,
                                              ushort* __restrict__ dst) {
  __shared__ float tile[64][65];
  int tp = threadIdx.x & 63, tq = threadIdx.x >> 6;
  int p0 = blockIdx.x * 64, c0 = blockIdx.y * 64, b = blockIdx.z;
#pragma unroll 4
  for (int i = 0; i < 16; ++i) {
    int ch = tq * 16 + i;
    tile[ch][tp] = src[((size_t)b * 256 + c0 + ch) * HWP + p0 + tp];
  }
  __syncthreads();
#pragma unroll 4
  for (int i = 0; i < 16; ++i) {
    int pp = tq * 16 + i;
    dst[((size_t)b * HWP + p0 + pp) * 256 + c0 + tp] = f2bf(tile[tp][pp]);
  }
}

// ---------------- MFMA GEMM: out_cc[b][p][o], tile 128p x (32*CT)o ----------------
template <typename TI, typename TO, bool LNF, bool RES, int CT>
__global__ __launch_bounds__(256) void k_gemmB(const TI* __restrict__ act,
                                               const ushort* __restrict__ Wbf,
                                               const float* __restrict__ ms,
                                               const float* __restrict__ rs,
                                               const float* __restrict__ sg,
                                               const float* __restrict__ wb,
                                               const float* __restrict__ bias,
                                               const ushort* __restrict__ resid,
                                               TO* __restrict__ outp, int K, int O) {
  __shared__ ushort at[128][56];       // padded: 112 B row stride (16B-aligned)
  __shared__ ushort wt[32 * CT][56];
  int tid = threadIdx.x;
  int lane = tid & 63, wv = tid >> 6;
  int wr = wv >> 1, wc = wv & 1;
  int p0 = blockIdx.x * 128, o0 = blockIdx.y * (32 * CT), b = blockIdx.z;
  size_t pb = (size_t)b * HWP;
  int l15 = lane & 15, lk = (lane >> 4) * 8;
  f32x4 acc[4][CT];
#pragma unroll
  for (int rt = 0; rt < 4; ++rt)
#pragma unroll
    for (int ct = 0; ct < CT; ++ct) { acc[rt][ct][0] = 0.f; acc[rt][ct][1] = 0.f; acc[rt][ct][2] = 0.f; acc[rt][ct][3] = 0.f; }

  for (int kb = 0; kb < K; kb += 32) {
    __syncthreads();
    {
      int p = tid >> 1, kh = (tid & 1) * 16;
      stage16(act + (pb + p0 + p) * (size_t)K + kb + kh, &at[p][kh]);
    }
    if (CT == 4) {
      int o = tid >> 1, kh = (tid & 1) * 16;
      stage16(Wbf + (size_t)(o0 + o) * K + kb + kh, &wt[o][kh]);
    } else if (tid < 128) {
      int o = tid >> 1, kh = (tid & 1) * 16;
      stage16(Wbf + (size_t)(o0 + o) * K + kb + kh, &wt[o][kh]);
    }
    __syncthreads();
    short8v a[4], bb[CT];
#pragma unroll
    for (int rt = 0; rt < 4; ++rt) a[rt] = *(const short8v*)&at[wr * 64 + rt * 16 + l15][lk];
#pragma unroll
    for (int ct = 0; ct < CT; ++ct) bb[ct] = *(const short8v*)&wt[wc * (16 * CT) + ct * 16 + l15][lk];
#pragma unroll
    for (int rt = 0; rt < 4; ++rt)
#pragma unroll
      for (int ct = 0; ct < CT; ++ct)
        acc[rt][ct] = __builtin_amdgcn_mfma_f32_16x16x32_bf16(a[rt], bb[ct], acc[rt][ct], 0, 0, 0);
  }
  // epilogue: D col(lane&15)=o, row((lane>>4)*4+j)=p  [m89-verified mapping]
#pragma unroll
  for (int rt = 0; rt < 4; ++rt) {
    int pbase = p0 + wr * 64 + rt * 16 + (lane >> 4) * 4;
#pragma unroll
    for (int j = 0; j < 4; ++j) {
      int p = pbase + j;
      float rr = 0.f, mm = 0.f;
      if (LNF) { rr = rs[b * HWP + p]; mm = ms[b * HWP + p]; }
#pragma unroll
      for (int ct = 0; ct < CT; ++ct) {
        int o = o0 + wc * (16 * CT) + ct * 16 + l15;
        float v = acc[rt][ct][j];
        if (LNF) v = rr * v - rr * mm * sg[o];
        if (wb) v += wb[o];
        if (bias) v += bias[o];
        if (RES) v += bf2f(resid[(pb + p) * (size_t)O + o]);
        stf(&outp[(pb + p) * (size_t)O + o], v);
      }
    }
  }
}

// ---------------- q1 slice of qkv1cc -> planar f32 (x8 to unscale) ----------------
__global__ __launch_bounds__(256) void k_q1p(const float* __restrict__ qkv1cc,
                                             float* __restrict__ q1p) {
  __shared__ float tile[64][65];
  int tp = threadIdx.x & 63, tq = threadIdx.x >> 6;
  int p0 = blockIdx.x * 64, b = blockIdx.y;
#pragma unroll 4
  for (int i = 0; i < 16; ++i) {
    int pp = tq * 16 + i;
    tile[tp][pp] = qkv1cc[((size_t)b * HWP + p0 + pp) * 192 + tp];
  }
  __syncthreads();
#pragma unroll 4
  for (int i = 0; i < 16; ++i) {
    int ch = tq * 16 + i;
    q1p[((size_t)b * 64 + ch) * HWP + p0 + tp] = tile[ch][tp] * 8.f;
  }
}

// ---------------- pack K,V (bf16 pair in u32) for the gather ----------------
// kvpack[s*4*HWP + b*HWP + p][l] = k_bf16 | (v_bf16 << 16)
__global__ __launch_bounds__(256) void k_packkv(const float* __restrict__ qkv1cc,
                                                const float* __restrict__ kv2cc,
                                                uint* __restrict__ kvpack) {
  int pix = blockIdx.x * 4 + (threadIdx.x >> 6);  // b*HWP+p
  int l = threadIdx.x & 63;
  const float* r1 = qkv1cc + (size_t)pix * 192;
  kvpack[(size_t)pix * 64 + l] =
      (uint)f2bf(r1[64 + l]) | ((uint)f2bf(r1[128 + l]) << 16);
  const float* r2 = kv2cc + (size_t)pix * 128;
  kvpack[((size_t)4 * HWP + pix) * 64 + l] =
      (uint)f2bf(r2[l]) | ((uint)f2bf(r2[64 + l]) << 16);
}

// ---------------- offset branches: depthwise 3x3 on q1 (both branches, z=16) --------
__global__ __launch_bounds__(256) void k_dw3x3(const float* __restrict__ q1p,
                                               const float* __restrict__ dww1,
                                               const float* __restrict__ dww2,
                                               float* __restrict__ t) {
  int p = blockIdx.x * 256 + threadIdx.x;
  int c = blockIdx.y, z = blockIdx.z;   // z = s*8 + bg
  int bg = z & 7;
  int b = bg >> 1, g = bg & 1;
  const float* dww = (z >= 8) ? dww2 : dww1;
  int y = p / WWD, x = p % WWD;
  const float* src = q1p + ((size_t)b * 64 + g * 32 + c) * HWP;
  float acc = 0.f;
#pragma unroll
  for (int ky = 0; ky < 3; ++ky) {
    int yy = y + ky - 1;
    if (yy < 0 || yy >= HH) continue;
#pragma unroll
    for (int kx = 0; kx < 3; ++kx) {
      int xx = x + kx - 1;
      if (xx < 0 || xx >= WWD) continue;
      acc += src[yy * WWD + xx] * dww[c * 9 + ky * 3 + kx];
    }
  }
  t[(size_t)(z * 32 + c) * HWP + p] = acc;
}

// ---------------- offset branches: LN(32ch) + exact GELU, in place, z=16 ------------
__global__ __launch_bounds__(256) void k_ln_gelu32(float* __restrict__ t,
                                                   const float* __restrict__ g1,
                                                   const float* __restrict__ b1,
                                                   const float* __restrict__ g2,
                                                   const float* __restrict__ b2) {
  int idx = blockIdx.x * 256 + threadIdx.x;  // over 16*HW
  int z = idx / HWP, p = idx % HWP;
  const float* g = (z >= 8) ? g2 : g1;
  const float* bb = (z >= 8) ? b2 : b1;
  float* base = t + (size_t)z * 32 * HWP + p;
  float s = 0.f, ss = 0.f;
#pragma unroll
  for (int c = 0; c < 32; ++c) { float v = base[(size_t)c * HWP]; s += v; ss += v * v; }
  float m = s / 32.f;
  float var = ss / 32.f - m * m;
  float r = rsqrtf(var + EPSV);
#pragma unroll
  for (int c = 0; c < 32; ++c) {
    float v = base[(size_t)c * HWP];
    float xn = (v - m) * r * g[c] + bb[c];
    base[(size_t)c * HWP] = 0.5f * xn * (1.f + erff(xn * 0.70710678118654752f));
  }
}

// ---------------- offset branches: 3x3 conv 32->18, tanh*RF + base ----------------
__global__ __launch_bounds__(256) void k_conv18(const float* __restrict__ t,
                                                const float* __restrict__ w1,
                                                const float* __restrict__ b1,
                                                const float* __restrict__ w2,
                                                const float* __restrict__ b2,
                                                float* __restrict__ offo) {
  __shared__ float in_t[32 * 324];  // 41.5 KB
  int tid = threadIdx.x;
  int tile = blockIdx.x, z = blockIdx.y;  // z = s*8 + bg
  int ty0 = (tile / 6) * 16, tx0 = (tile % 6) * 16;
  const float* w = (z >= 8) ? w2 : w1;
  const float* bias = (z >= 8) ? b2 : b1;
  const float* tb = t + (size_t)z * 32 * HWP;
  for (int idx = tid; idx < 32 * 324; idx += 256) {
    int c = idx / 324, pp = idx % 324;
    int gy = ty0 - 1 + pp / 18, gx = tx0 - 1 + pp % 18;
    float v = 0.f;
    if (gy >= 0 && gy < HH && gx >= 0 && gx < WWD) v = tb[(size_t)c * HWP + gy * WWD + gx];
    in_t[idx] = v;
  }
  __syncthreads();
  int ly = tid >> 4, lx = tid & 15;
  float acc[18];
#pragma unroll
  for (int oc = 0; oc < 18; ++oc) acc[oc] = bias[oc];
  const float* basep = in_t + ly * 18 + lx;
  for (int c = 0; c < 32; ++c) {
#pragma unroll
    for (int dy = 0; dy < 3; ++dy)
#pragma unroll
      for (int dx = 0; dx < 3; ++dx) {
        float v = basep[c * 324 + dy * 18 + dx];
        int tap = c * 9 + dy * 3 + dx;
#pragma unroll
        for (int oc = 0; oc < 18; ++oc)
          acc[oc] = fmaf(v, w[oc * 288 + tap], acc[oc]);
      }
  }
  int p = (ty0 + ly) * WWD + tx0 + lx;
#pragma unroll
  for (int oc = 0; oc < 18; ++oc) {
    int n = oc >> 1, d = oc & 1;
    float basev = d ? (float)(n % 3 - 1) : (float)(n / 3 - 1);
    offo[((size_t)z * 18 + oc) * HWP + p] = tanhf(acc[oc]) * RFV + basev;
  }
}

// ---------------- fused deformable sampling + softmax + PV ----------------
__global__ __launch_bounds__(256) void k_attn(const float* __restrict__ qkv1cc,
                                              const uint* __restrict__ kvpack,
                                              const float* __restrict__ offo,
                                              const float* __restrict__ rpb,
                                              ushort* __restrict__ o_att) {
  __shared__ float rl[576];
  for (int i = threadIdx.x; i < 576; i += 256) rl[i] = rpb[i];
  __syncthreads();
  int pix = blockIdx.x * 4 + (threadIdx.x >> 6);
  int l = threadIdx.x & 63;
  int b = pix / HWP, p = pix % HWP;
  int y = p / WWD, x = p % WWD;
  int g = l >> 5;
  int bg = b * 2 + g;
  float qv = qkv1cc[((size_t)b * HWP + p) * 192 + l];
  float scores[18], vvv[18];
#pragma unroll
  for (int s = 0; s < 2; ++s) {
    const float* offp = offo + ((size_t)(s * 8 + bg) * 18) * HWP + p;
    const uint* kvb = kvpack + ((size_t)(s * 4 + b) * HWP) * 64;
#pragma unroll
    for (int n = 0; n < 9; ++n) {
      float ry = (float)y + offp[(size_t)(2 * n) * HWP];
      float rx = (float)x + offp[(size_t)(2 * n + 1) * HWP];
      float y0f = floorf(ry), x0f = floorf(rx);
      float wy = ry - y0f, wx = rx - x0f;
      int y0 = (int)y0f, x0 = (int)x0f;
      float ka = 0.f, va = 0.f;
#pragma unroll
      for (int cy = 0; cy < 2; ++cy) {
        int yi = y0 + cy;
        if (yi < 0 || yi >= HH) continue;
        float wyc = cy ? wy : 1.f - wy;
#pragma unroll
        for (int cx = 0; cx < 2; ++cx) {
          int xi = x0 + cx;
          if (xi < 0 || xi >= WWD) continue;
          float wgt = wyc * (cx ? wx : 1.f - wx);
          uint kv = kvb[(size_t)(yi * WWD + xi) * 64 + l];
          ka += wgt * bf2f((ushort)(kv & 0xFFFFu));
          va += wgt * bf2f((ushort)(kv >> 16));
        }
      }
      float sp = qv * (ka + rl[n * 64 + l]);
      sp += __shfl_xor(sp, 1);
      sp += __shfl_xor(sp, 2);
      sp += __shfl_xor(sp, 4);
      sp += __shfl_xor(sp, 8);
      sp += __shfl_xor(sp, 16);
      sp += __shfl_xor(sp, 32);
      scores[s * 9 + n] = sp;
      vvv[s * 9 + n] = va;
    }
  }
  float mx = scores[0];
#pragma unroll
  for (int i = 1; i < 18; ++i) mx = fmaxf(mx, scores[i]);
  float sum = 0.f;
#pragma unroll
  for (int i = 0; i < 18; ++i) { scores[i] = expf(scores[i] - mx); sum += scores[i]; }
  float inv = 1.f / sum;
  float o = 0.f;
#pragma unroll
  for (int i = 0; i < 18; ++i) o += scores[i] * vvv[i];
  o_att[((size_t)b * HWP + p) * 64 + l] = f2bf(o * inv);
}

// ---------------- depthwise 3x3 + gelu(h+hd), channel-contiguous bf16 ----------------
__global__ __launch_bounds__(256) void k_dwgelu_cc(const ushort* __restrict__ h,
                                                   const float* __restrict__ w,
                                                   const float* __restrict__ bias,
                                                   ushort* __restrict__ h2) {
  __shared__ ushort tileh[324][48];  // 18x18 px halo tile x 32 ch (96 B rows, aligned)
  __shared__ float wl[32][9];
  __shared__ float bl[32];
  int tid = threadIdx.x;
  int tile = blockIdx.x, chb = blockIdx.y, b = blockIdx.z;
  int ty0 = (tile / 6) * 16, tx0 = (tile % 6) * 16;
  size_t base = ((size_t)b * HWP) * 1024 + chb * 32;
  for (int i = tid; i < 288; i += 256) wl[i / 9][i % 9] = w[(chb * 32 + i / 9) * 9 + i % 9];
  if (tid < 32) bl[tid] = bias[chb * 32 + tid];
  for (int idx = tid; idx < 324; idx += 256) {
    int py = idx / 18, px = idx % 18;
    int gy = ty0 - 1 + py, gx = tx0 - 1 + px;
    ushort8v* d = (ushort8v*)&tileh[idx][0];
    if (gy >= 0 && gy < HH && gx >= 0 && gx < WWD) {
      const ushort8v* sv = (const ushort8v*)(h + base + (size_t)(gy * WWD + gx) * 1024);
      d[0] = sv[0]; d[1] = sv[1]; d[2] = sv[2]; d[3] = sv[3];
    } else {
      ushort8v z;
#pragma unroll
      for (int e = 0; e < 8; ++e) z[e] = 0;
      d[0] = z; d[1] = z; d[2] = z; d[3] = z;
    }
  }
  __syncthreads();
  int ly = tid >> 4, lx = tid & 15;
  float a[32];
#pragma unroll
  for (int c = 0; c < 32; ++c) a[c] = bl[c];
#pragma unroll
  for (int dy = 0; dy < 3; ++dy)
#pragma unroll
    for (int dx = 0; dx < 3; ++dx) {
      const ushort8v* t = (const ushort8v*)&tileh[(ly + dy) * 18 + lx + dx][0];
      int tap = dy * 3 + dx;
#pragma unroll
      for (int cq = 0; cq < 4; ++cq) {
        ushort8v vv = t[cq];
#pragma unroll
        for (int e = 0; e < 8; ++e) a[cq * 8 + e] += bf2f(vv[e]) * wl[cq * 8 + e][tap];
      }
    }
  const ushort8v* ctr = (const ushort8v*)&tileh[(ly + 1) * 18 + lx + 1][0];
  ushort8v* outv = (ushort8v*)(h2 + base + (size_t)((ty0 + ly) * WWD + tx0 + lx) * 1024);
#pragma unroll
  for (int cq = 0; cq < 4; ++cq) {
    ushort8v vv = ctr[cq];
    ushort8v rv;
#pragma unroll
    for (int e = 0; e < 8; ++e) {
      float v = bf2f(vv[e]) + a[cq * 8 + e];
      rv[e] = f2bf(0.5f * v * (1.f + erff(v * 0.70710678118654752f)));
    }
    outv[cq] = rv;
  }
}

// ---------------- final: out_planar = fc2cc + o1cc (transpose-add) ----------------
__global__ __launch_bounds__(256) void k_fromcc(const float* __restrict__ fc2cc,
                                                const float* __restrict__ o1cc,
                                                float* __restrict__ outp) {
  __shared__ float tile[64][65];
  int tp = threadIdx.x & 63, tq = threadIdx.x >> 6;
  int p0 = blockIdx.x * 64, c0 = blockIdx.y * 64, b = blockIdx.z;
#pragma unroll 4
  for (int i = 0; i < 16; ++i) {
    int pp = tq * 16 + i;
    size_t idx = ((size_t)b * HWP + p0 + pp) * 256 + c0 + tp;
    tile[tp][pp] = fc2cc[idx] + o1cc[idx];
  }
  __syncthreads();
#pragma unroll 4
  for (int i = 0; i < 16; ++i) {
    int ch = tq * 16 + i;
    outp[((size_t)b * 256 + c0 + ch) * HWP + p0 + tp] = tile[ch][tp];
  }
}

extern "C" void kernel_launch(void* const* d_in, const int* in_sizes, int n_in,
                              void* d_out, int out_size, void* d_ws, size_t ws_size,
                              hipStream_t stream) {
  const float* x      = (const float*)d_in[0];
  const float* y      = (const float*)d_in[1];
  const float* g11    = (const float*)d_in[2];
  const float* b11    = (const float*)d_in[3];
  const float* g21    = (const float*)d_in[4];
  const float* b21    = (const float*)d_in[5];
  const float* g12    = (const float*)d_in[6];
  const float* b12    = (const float*)d_in[7];
  const float* w_qkv1 = (const float*)d_in[8];
  const float* w_qkv2 = (const float*)d_in[9];
  const float* o1dw   = (const float*)d_in[10];
  const float* o1lg   = (const float*)d_in[11];
  const float* o1lb   = (const float*)d_in[12];
  const float* o1w    = (const float*)d_in[13];
  const float* o1bi   = (const float*)d_in[14];
  const float* o2dw   = (const float*)d_in[15];
  const float* o2lg   = (const float*)d_in[16];
  const float* o2lb   = (const float*)d_in[17];
  const float* o2w    = (const float*)d_in[18];
  const float* o2bi   = (const float*)d_in[19];
  const float* rpb    = (const float*)d_in[20];
  const float* proj_w = (const float*)d_in[21];
  const float* proj_b = (const float*)d_in[22];
  const float* fc1_w  = (const float*)d_in[23];
  const float* fc1_b  = (const float*)d_in[24];
  const float* dw_w   = (const float*)d_in[25];
  const float* dw_b   = (const float*)d_in[26];
  const float* fc2_w  = (const float*)d_in[27];
  const float* fc2_b  = (const float*)d_in[28];
  float* out = (float*)d_out;

  // ---- workspace layout (word offsets; aliased by live range) ----
  float* ws = (float*)d_ws;
  ushort* xcc   = (ushort*)(ws + 0);           // 9,437,184 bf16
  ushort* ycc   = (ushort*)(ws + 4718592);     // 9,437,184 bf16
  float*  q1p   = ws + 4718592;                // 2,359,296 f32 (after ycc dead)
  float*  qkv1cc= ws + 9437184;                // 7,077,888 f32
  float*  kv2cc = ws + 16515072;               // 4,718,592 f32
  float*  offb  = ws + 21233664;               // 2,654,208 f32
  ushort* o_att = (ushort*)(ws + 23887872);    // 2,359,296 bf16 (half the slot)
  float*  tbuf12= ws + 26247168;               // 4,718,592 f32 (both offset branches)
  uint*   kvpack= (uint*)(ws + 30965760);      // 4,718,592 u32 (packed bf16 K|V)
  ushort* hcc   = (ushort*)(ws + 0);           // 37,748,736 bf16 (stage 2)
  ushort* h2cc  = (ushort*)(ws + 18874368);    // 37,748,736 bf16
  float*  o1cc  = ws + 37748736;               // 9,437,184 f32
  float*  fc2cc = ws + 0;                      // 9,437,184 f32 (after hcc dead)
  const size_t SW = 47185920;
  float* m_x = ws + SW, *r_x = m_x + 36864, *m_y = r_x + 36864, *r_y = m_y + 36864;
  float* m_o = r_y + 36864, *r_o = m_o + 36864;
  ushort* Wg1bf = (ushort*)(ws + SW + 221184);      // 49,152 bf16
  float* sg1 = ws + SW + 245760, *wb1 = sg1 + 192;
  ushort* Wg2bf = (ushort*)(ws + SW + 246144);      // 32,768 bf16
  float* sg2 = ws + SW + 262528, *wb2 = sg2 + 128;
  ushort* Wgfbf = (ushort*)(ws + SW + 262784);      // 262,144 bf16
  float* sgf = ws + SW + 393856, *wbf = sgf + 1024;
  ushort* projbf = (ushort*)(ws + SW + 395904);     // 16,384 bf16
  ushort* fc2bf  = (ushort*)(ws + SW + 404096);     // 262,144 bf16

  // 1. weights -> bf16 (+LN fold); SCALE=0.125 folded into q rows of qkv1.
  k_prepbf<<<48, 256, 0, stream>>>(w_qkv1, g11, b11, Wg1bf, sg1, wb1, 192, 256, 64);
  k_prepbf<<<32, 256, 0, stream>>>(w_qkv2, g21, b21, Wg2bf, sg2, wb2, 128, 256, 0);
  k_prepbf<<<256, 256, 0, stream>>>(fc1_w, g12, b12, Wgfbf, sgf, wbf, 1024, 256, 0);
  k_prepbf<<<64, 256, 0, stream>>>(proj_w, nullptr, nullptr, projbf, nullptr, nullptr, 256, 64, 0);
  k_prepbf<<<64, 256, 0, stream>>>(fc2_w, nullptr, nullptr, fc2bf, nullptr, nullptr, 256, 1024, 0);

  // 2. LN stats + cc-bf16 activations
  k_ln_stats<<<144, 256, 0, stream>>>(x, m_x, r_x, 256);
  k_ln_stats<<<144, 256, 0, stream>>>(y, m_y, r_y, 256);
  k_tocc<<<dim3(144, 4, 4), 256, 0, stream>>>(x, xcc);
  k_tocc<<<dim3(144, 4, 4), 256, 0, stream>>>(y, ycc);

  // 3. qkv projections (MFMA, LN folded)
  k_gemmB<ushort, float, true, false, 2><<<dim3(72, 3, 4), 256, 0, stream>>>(
      xcc, Wg1bf, m_x, r_x, sg1, wb1, nullptr, nullptr, qkv1cc, 256, 192);
  k_gemmB<ushort, float, true, false, 4><<<dim3(72, 1, 4), 256, 0, stream>>>(
      ycc, Wg2bf, m_y, r_y, sg2, wb2, nullptr, nullptr, kv2cc, 256, 128);

  // 4. offset branches (both fused per kernel; z = s*8+bg) + K/V pack
  k_q1p<<<dim3(144, 4), 256, 0, stream>>>(qkv1cc, q1p);
  k_packkv<<<9216, 256, 0, stream>>>(qkv1cc, kv2cc, kvpack);
  k_dw3x3<<<dim3(36, 32, 16), 256, 0, stream>>>(q1p, o1dw, o2dw, tbuf12);
  k_ln_gelu32<<<576, 256, 0, stream>>>(tbuf12, o1lg, o1lb, o2lg, o2lb);
  k_conv18<<<dim3(36, 16), 256, 0, stream>>>(tbuf12, o1w, o1bi, o2w, o2bi, offb);

  // 5. fused deformable sampling + attention (bf16 packed K/V gather)
  k_attn<<<9216, 256, 0, stream>>>(qkv1cc, kvpack, offb, rpb, o_att);

  // 6. proj (MFMA) + residual(xcc)
  k_gemmB<ushort, float, false, true, 4><<<dim3(72, 2, 4), 256, 0, stream>>>(
      o_att, projbf, nullptr, nullptr, nullptr, nullptr, proj_b, xcc, o1cc, 64, 256);

  // 7. MLP: LN stats, fc1 (MFMA, LN folded, bf16 out), dw+gelu cc, fc2 (MFMA)
  k_ln_stats_cc<<<9216, 256, 0, stream>>>(o1cc, m_o, r_o);
  k_gemmB<float, ushort, true, false, 4><<<dim3(72, 8, 4), 256, 0, stream>>>(
      o1cc, Wgfbf, m_o, r_o, sgf, wbf, fc1_b, nullptr, hcc, 256, 1024);
  k_dwgelu_cc<<<dim3(36, 32, 4), 256, 0, stream>>>(hcc, dw_w, dw_b, h2cc);
  k_gemmB<ushort, float, false, false, 4><<<dim3(72, 2, 4), 256, 0, stream>>>(
      h2cc, fc2bf, nullptr, nullptr, nullptr, nullptr, fc2_b, nullptr, fc2cc, 1024, 256);

  // 8. final transpose + residual(o1cc)
  k_fromcc<<<dim3(144, 4, 4), 256, 0, stream>>>(fc2cc, o1cc, out);
}